// Round 3
// baseline (42.159 us; speedup 1.0000x reference)
//
#include <hip/hip_runtime.h>

typedef float v4f __attribute__((ext_vector_type(4)));

// 45-tap palindromic filter, padded to 48 with zeros so every phase uses a
// uniform 12-tap loop: out phase p uses weight BASE48[4*j + 3 - p].
constexpr float BASE48[48] = {
    -0.00463495665f, -0.00363442646f, 3.84904063e-18f, 0.00576678319f, 0.0108358664f,
    0.010198079f, -9.31747402e-18f, -0.0175033181f, -0.0317660068f, -0.0284531643f,
    1.85181518e-17f, 0.0442450253f, 0.0771733386f, 0.067055491f, -2.85299239e-17f,
    -0.101548683f, -0.178708388f, -0.160004642f, 3.61741232e-17f, 0.287940558f,
    0.625431459f, 0.8970676f, 1.00107877f, 0.8970676f, 0.625431459f, 0.287940558f,
    3.61741232e-17f, -0.160004642f, -0.178708388f, -0.101548683f, -2.85299239e-17f,
    0.067055491f, 0.0771733386f, 0.0442450253f, 1.85181518e-17f, -0.0284531643f,
    -0.0317660068f, -0.0175033181f, -9.31747402e-18f, 0.010198079f, 0.0108358664f,
    0.00576678319f, 3.84904063e-18f, -0.00363442646f, -0.00463495665f,
    0.0f, 0.0f, 0.0f
};

__device__ __forceinline__ void fma4(v4f& a, float w, const v4f& v) {
    a.x = fmaf(w, v.x, a.x);
    a.y = fmaf(w, v.y, a.y);
    a.z = fmaf(w, v.z, a.z);
    a.w = fmaf(w, v.w, a.w);
}

// One block computes a 128x128 output tile for one (b,c) image.
// Output o (per axis): phase p = o&3, m = o>>2; input i = m - 5 + j, j in [0,12),
// weight BASE48[4*j + 3 - p]. Input halo: [m0 - 5, m0 + 32 + 6) -> 43 samples.
__launch_bounds__(256)
__global__ void upfirdn4_sep_kernel(const float* __restrict__ x,
                                    float* __restrict__ out) {
    constexpr int H = 128, W = 128, OW = 512, OH = 512;
    constexpr int TSTRIDE = 132;     // tmp row stride (floats); 528 B, 16B-aligned

    __shared__ float in_s[43][44];        // 43x43 input halo (+1 pad col)
    __shared__ float tmp[43][TSTRIDE];    // horizontal-pass result: 43 rows x 128 cols

    const int tid = threadIdx.x;
    const int bc  = blockIdx.z;               // b*8 + c
    const int OX  = blockIdx.x * 128;
    const int OY  = blockIdx.y * 128;
    const int I0x = (OX >> 2) - 5;
    const int I0y = (OY >> 2) - 5;

    const float* xb = x + (size_t)bc * (H * W);

    // ---- stage input halo tile (zero-pad out-of-range) ----
    for (int t = tid; t < 43 * 44; t += 256) {
        int r = t / 44;
        int c = t - r * 44;
        int iy = I0y + r;
        int ix = I0x + c;
        float v = 0.0f;
        if ((unsigned)iy < (unsigned)H && (unsigned)ix < (unsigned)W)
            v = xb[iy * W + ix];
        in_s[r][c] = v;
    }
    __syncthreads();

    // ---- horizontal polyphase pass: tmp[row][0..128), rows 0..42 ----
    // Each item computes 4 consecutive output cols (phases 0..3) sharing the
    // same 12 input samples in_s[row][m..m+11].
    for (int t = tid; t < 43 * 32; t += 256) {
        int row = t >> 5;
        int m   = t & 31;
        float a0 = 0.f, a1 = 0.f, a2 = 0.f, a3 = 0.f;
#pragma unroll
        for (int j = 0; j < 12; ++j) {
            float v = in_s[row][m + j];
            a0 = fmaf(BASE48[4 * j + 3], v, a0);  // phase 0
            a1 = fmaf(BASE48[4 * j + 2], v, a1);  // phase 1
            a2 = fmaf(BASE48[4 * j + 1], v, a2);  // phase 2
            a3 = fmaf(BASE48[4 * j + 0], v, a3);  // phase 3
        }
        v4f r4 = {a0, a1, a2, a3};
        *(v4f*)&tmp[row][m << 2] = r4;
    }
    __syncthreads();

    // ---- vertical polyphase pass: each thread does 4 patches of 4x4 ----
    // Patch (py, px): out rows 4*py+p, cols 4*px..4*px+3; reads tmp rows
    // [py, py+12) at col 4*px — 12 float4 LDS reads shared across 4 phases.
#pragma unroll
    for (int it = 0; it < 4; ++it) {
        int pidx = tid + it * 256;
        int py = pidx >> 5;
        int oc = (pidx & 31) << 2;
        v4f acc0 = {0, 0, 0, 0}, acc1 = {0, 0, 0, 0};
        v4f acc2 = {0, 0, 0, 0}, acc3 = {0, 0, 0, 0};
#pragma unroll
        for (int j = 0; j < 12; ++j) {
            v4f v = *(const v4f*)&tmp[py + j][oc];
            fma4(acc0, BASE48[4 * j + 3], v);  // phase 0
            fma4(acc1, BASE48[4 * j + 2], v);  // phase 1
            fma4(acc2, BASE48[4 * j + 1], v);  // phase 2
            fma4(acc3, BASE48[4 * j + 0], v);  // phase 3
        }
        size_t base = (size_t)bc * (OH * OW) + (size_t)(OY + (py << 2)) * OW + (OX + oc);
        __builtin_nontemporal_store(acc0, (v4f*)&out[base]);
        __builtin_nontemporal_store(acc1, (v4f*)&out[base + OW]);
        __builtin_nontemporal_store(acc2, (v4f*)&out[base + 2 * OW]);
        __builtin_nontemporal_store(acc3, (v4f*)&out[base + 3 * OW]);
    }
}

extern "C" void kernel_launch(void* const* d_in, const int* in_sizes, int n_in,
                              void* d_out, int out_size, void* d_ws, size_t ws_size,
                              hipStream_t stream) {
    const float* x = (const float*)d_in[0];
    float* out = (float*)d_out;
    dim3 grid(4, 4, 128);   // 4x4 tiles of 128x128 over 512x512, z = B*C = 128
    dim3 block(256);
    upfirdn4_sep_kernel<<<grid, block, 0, stream>>>(x, out);
}

// Round 4
// 37.281 us; speedup vs baseline: 1.1308x; 1.1308x over previous
//
#include <hip/hip_runtime.h>

typedef float v4f __attribute__((ext_vector_type(4)));

// 45-tap palindromic filter, padded to 48 with zeros so every phase uses a
// uniform 12-tap loop: out phase p uses weight BASE48[4*j + 3 - p].
constexpr float BASE48[48] = {
    -0.00463495665f, -0.00363442646f, 3.84904063e-18f, 0.00576678319f, 0.0108358664f,
    0.010198079f, -9.31747402e-18f, -0.0175033181f, -0.0317660068f, -0.0284531643f,
    1.85181518e-17f, 0.0442450253f, 0.0771733386f, 0.067055491f, -2.85299239e-17f,
    -0.101548683f, -0.178708388f, -0.160004642f, 3.61741232e-17f, 0.287940558f,
    0.625431459f, 0.8970676f, 1.00107877f, 0.8970676f, 0.625431459f, 0.287940558f,
    3.61741232e-17f, -0.160004642f, -0.178708388f, -0.101548683f, -2.85299239e-17f,
    0.067055491f, 0.0771733386f, 0.0442450253f, 1.85181518e-17f, -0.0284531643f,
    -0.0317660068f, -0.0175033181f, -9.31747402e-18f, 0.010198079f, 0.0108358664f,
    0.00576678319f, 3.84904063e-18f, -0.00363442646f, -0.00463495665f,
    0.0f, 0.0f, 0.0f
};

__device__ __forceinline__ void fma4(v4f& a, float w, const v4f& v) {
    a.x = fmaf(w, v.x, a.x);
    a.y = fmaf(w, v.y, a.y);
    a.z = fmaf(w, v.z, a.z);
    a.w = fmaf(w, v.w, a.w);
}

// One block computes a 128x128 output tile for one (b,c) image.
// Output o (per axis): phase p = o&3, m = o>>2; input i = m - 5 + j, j in [0,12),
// weight BASE48[4*j + 3 - p]. Input halo: [m0 - 5, m0 + 32 + 6) -> 43 samples.
__launch_bounds__(256)
__global__ void upfirdn4_sep_kernel(const float* __restrict__ x,
                                    float* __restrict__ out) {
    constexpr int H = 128, W = 128, OW = 512, OH = 512;
    constexpr int TSTRIDE = 132;     // tmp row stride (floats); 528 B, 16B-aligned

    __shared__ float in_s[43][44];        // 43x43 input halo (+1 pad col)
    __shared__ float tmp[43][TSTRIDE];    // horizontal-pass result: 43 rows x 128 cols

    const int tid = threadIdx.x;
    const int bc  = blockIdx.z;               // b*8 + c
    const int OX  = blockIdx.x * 128;
    const int OY  = blockIdx.y * 128;
    const int I0x = (OX >> 2) - 5;
    const int I0y = (OY >> 2) - 5;

    const float* xb = x + (size_t)bc * (H * W);

    // ---- stage input halo tile (zero-pad out-of-range) ----
    for (int t = tid; t < 43 * 44; t += 256) {
        int r = t / 44;
        int c = t - r * 44;
        int iy = I0y + r;
        int ix = I0x + c;
        float v = 0.0f;
        if ((unsigned)iy < (unsigned)H && (unsigned)ix < (unsigned)W)
            v = xb[iy * W + ix];
        in_s[r][c] = v;
    }
    __syncthreads();

    // ---- horizontal polyphase pass: tmp[row][0..128), rows 0..42 ----
    // Each item computes 4 consecutive output cols (phases 0..3) sharing the
    // same 12 input samples in_s[row][m..m+11].
    for (int t = tid; t < 43 * 32; t += 256) {
        int row = t >> 5;
        int m   = t & 31;
        float a0 = 0.f, a1 = 0.f, a2 = 0.f, a3 = 0.f;
#pragma unroll
        for (int j = 0; j < 12; ++j) {
            float v = in_s[row][m + j];
            a0 = fmaf(BASE48[4 * j + 3], v, a0);  // phase 0
            a1 = fmaf(BASE48[4 * j + 2], v, a1);  // phase 1
            a2 = fmaf(BASE48[4 * j + 1], v, a2);  // phase 2
            a3 = fmaf(BASE48[4 * j + 0], v, a3);  // phase 3
        }
        v4f r4 = {a0, a1, a2, a3};
        *(v4f*)&tmp[row][m << 2] = r4;
    }
    __syncthreads();

    // ---- vertical polyphase pass: each thread does 4 patches of 4x4 ----
    // Patch (py, px): out rows 4*py+p, cols 4*px..4*px+3; reads tmp rows
    // [py, py+12) at col 4*px — 12 float4 LDS reads shared across 4 phases.
#pragma unroll
    for (int it = 0; it < 4; ++it) {
        int pidx = tid + it * 256;
        int py = pidx >> 5;
        int oc = (pidx & 31) << 2;
        v4f acc0 = {0, 0, 0, 0}, acc1 = {0, 0, 0, 0};
        v4f acc2 = {0, 0, 0, 0}, acc3 = {0, 0, 0, 0};
#pragma unroll
        for (int j = 0; j < 12; ++j) {
            v4f v = *(const v4f*)&tmp[py + j][oc];
            fma4(acc0, BASE48[4 * j + 3], v);  // phase 0
            fma4(acc1, BASE48[4 * j + 2], v);  // phase 1
            fma4(acc2, BASE48[4 * j + 1], v);  // phase 2
            fma4(acc3, BASE48[4 * j + 0], v);  // phase 3
        }
        size_t base = (size_t)bc * (OH * OW) + (size_t)(OY + (py << 2)) * OW + (OX + oc);
        *(v4f*)&out[base]          = acc0;
        *(v4f*)&out[base + OW]     = acc1;
        *(v4f*)&out[base + 2 * OW] = acc2;
        *(v4f*)&out[base + 3 * OW] = acc3;
    }
}

extern "C" void kernel_launch(void* const* d_in, const int* in_sizes, int n_in,
                              void* d_out, int out_size, void* d_ws, size_t ws_size,
                              hipStream_t stream) {
    const float* x = (const float*)d_in[0];
    float* out = (float*)d_out;
    dim3 grid(4, 4, 128);   // 4x4 tiles of 128x128 over 512x512, z = B*C = 128
    dim3 block(256);
    upfirdn4_sep_kernel<<<grid, block, 0, stream>>>(x, out);
}

// Round 5
// 37.079 us; speedup vs baseline: 1.1370x; 1.0054x over previous
//
#include <hip/hip_runtime.h>

typedef float v4f __attribute__((ext_vector_type(4)));

// 45-tap palindromic filter, padded to 48 with zeros so every phase uses a
// uniform 12-tap loop: out phase p uses weight BASE48[4*j + 3 - p].
constexpr float BASE48[48] = {
    -0.00463495665f, -0.00363442646f, 3.84904063e-18f, 0.00576678319f, 0.0108358664f,
    0.010198079f, -9.31747402e-18f, -0.0175033181f, -0.0317660068f, -0.0284531643f,
    1.85181518e-17f, 0.0442450253f, 0.0771733386f, 0.067055491f, -2.85299239e-17f,
    -0.101548683f, -0.178708388f, -0.160004642f, 3.61741232e-17f, 0.287940558f,
    0.625431459f, 0.8970676f, 1.00107877f, 0.8970676f, 0.625431459f, 0.287940558f,
    3.61741232e-17f, -0.160004642f, -0.178708388f, -0.101548683f, -2.85299239e-17f,
    0.067055491f, 0.0771733386f, 0.0442450253f, 1.85181518e-17f, -0.0284531643f,
    -0.0317660068f, -0.0175033181f, -9.31747402e-18f, 0.010198079f, 0.0108358664f,
    0.00576678319f, 3.84904063e-18f, -0.00363442646f, -0.00463495665f,
    0.0f, 0.0f, 0.0f
};

__device__ __forceinline__ void fma4(v4f& a, float w, const v4f& v) {
    a.x = fmaf(w, v.x, a.x);
    a.y = fmaf(w, v.y, a.y);
    a.z = fmaf(w, v.z, a.z);
    a.w = fmaf(w, v.w, a.w);
}

// One block computes a 128-wide x 64-tall output tile of one (b,c) image.
// Per axis: out o -> phase p = o&3, m = o>>2; input i = m - 5 + j, j in [0,12),
// weight BASE48[4*j + 3 - p].
// Halo: rows 27 (= 64/4 + 11), cols 43 (= 128/4 + 11).
// LDS = 27*44*4 + 27*132*4 = 19008 B -> 8 blocks/CU (wave-capped, 100% occ).
// Grid 4*8*128 = 4096 = exactly 2 rounds of 2048 resident blocks.
__launch_bounds__(256)
__global__ void upfirdn4_sep_kernel(const float* __restrict__ x,
                                    float* __restrict__ out) {
    constexpr int H = 128, W = 128, OW = 512, OH = 512;
    constexpr int HR = 27, HC = 43;      // halo rows/cols
    constexpr int TSTRIDE = 132;         // tmp row stride (floats), 16B-aligned

    __shared__ float in_s[HR][44];       // halo tile (+pad col)
    __shared__ float tmp[HR][TSTRIDE];   // horizontal-pass result: 27 x 128

    const int tid = threadIdx.x;
    const int bc  = blockIdx.z;              // b*8 + c
    const int OX  = blockIdx.x * 128;
    const int OY  = blockIdx.y * 64;
    const int I0x = (OX >> 2) - 5;
    const int I0y = (OY >> 2) - 5;

    const float* xb = x + (size_t)bc * (H * W);

    // ---- stage input halo tile ----
    const bool interior = (I0x >= 0) & (I0x + HC <= W) & (I0y >= 0) & (I0y + HR <= H);
    if (interior) {
        for (int t = tid; t < HR * HC; t += 256) {
            int r = t / HC;
            int c = t - r * HC;
            in_s[r][c] = xb[(I0y + r) * W + I0x + c];
        }
    } else {
        for (int t = tid; t < HR * HC; t += 256) {
            int r = t / HC;
            int c = t - r * HC;
            int iy = I0y + r;
            int ix = I0x + c;
            float v = 0.0f;
            if ((unsigned)iy < (unsigned)H && (unsigned)ix < (unsigned)W)
                v = xb[iy * W + ix];
            in_s[r][c] = v;
        }
    }
    __syncthreads();

    // ---- horizontal polyphase pass: tmp[row][0..128), rows 0..26 ----
    // Each item computes 4 consecutive output cols (phases 0..3) sharing the
    // same 12 input samples in_s[row][m..m+11].
    for (int t = tid; t < HR * 32; t += 256) {
        int row = t >> 5;
        int m   = t & 31;
        float a0 = 0.f, a1 = 0.f, a2 = 0.f, a3 = 0.f;
#pragma unroll
        for (int j = 0; j < 12; ++j) {
            float v = in_s[row][m + j];
            a0 = fmaf(BASE48[4 * j + 3], v, a0);  // phase 0
            a1 = fmaf(BASE48[4 * j + 2], v, a1);  // phase 1
            a2 = fmaf(BASE48[4 * j + 1], v, a2);  // phase 2
            a3 = fmaf(BASE48[4 * j + 0], v, a3);  // phase 3
        }
        v4f r4 = {a0, a1, a2, a3};
        *(v4f*)&tmp[row][m << 2] = r4;
    }
    __syncthreads();

    // ---- vertical polyphase pass: each thread does 2 patches of 4x4 ----
    // Patch (py, px): out rows 4*py+p, cols 4*px..4*px+3; reads tmp rows
    // [py, py+12) at col 4*px — 12 float4 LDS reads shared across 4 phases.
#pragma unroll
    for (int it = 0; it < 2; ++it) {
        int pidx = tid + it * 256;
        int py = pidx >> 5;
        int oc = (pidx & 31) << 2;
        v4f acc0 = {0, 0, 0, 0}, acc1 = {0, 0, 0, 0};
        v4f acc2 = {0, 0, 0, 0}, acc3 = {0, 0, 0, 0};
#pragma unroll
        for (int j = 0; j < 12; ++j) {
            v4f v = *(const v4f*)&tmp[py + j][oc];
            fma4(acc0, BASE48[4 * j + 3], v);  // phase 0
            fma4(acc1, BASE48[4 * j + 2], v);  // phase 1
            fma4(acc2, BASE48[4 * j + 1], v);  // phase 2
            fma4(acc3, BASE48[4 * j + 0], v);  // phase 3
        }
        size_t base = (size_t)bc * (OH * OW) + (size_t)(OY + (py << 2)) * OW + (OX + oc);
        *(v4f*)&out[base]          = acc0;
        *(v4f*)&out[base + OW]     = acc1;
        *(v4f*)&out[base + 2 * OW] = acc2;
        *(v4f*)&out[base + 3 * OW] = acc3;
    }
}

extern "C" void kernel_launch(void* const* d_in, const int* in_sizes, int n_in,
                              void* d_out, int out_size, void* d_ws, size_t ws_size,
                              hipStream_t stream) {
    const float* x = (const float*)d_in[0];
    float* out = (float*)d_out;
    dim3 grid(4, 8, 128);   // 128x64 tiles over 512x512, z = B*C = 128
    dim3 block(256);
    upfirdn4_sep_kernel<<<grid, block, 0, stream>>>(x, out);
}